// Round 8
// baseline (222.347 us; speedup 1.0000x reference)
//
#include <hip/hip_runtime.h>
#include <math.h>

#define N_NODES 50000
#define N_EDGES 800000

typedef __attribute__((ext_vector_type(8))) short bf16x8;
typedef __attribute__((ext_vector_type(4))) float f32x4;

// round-to-nearest-even float -> bf16 (bits in low 16)
__device__ __forceinline__ unsigned f2bfu(float f) {
  union { float f; unsigned u; } v; v.f = f;
  return (v.u + 0x7FFFu + ((v.u >> 16) & 1u)) >> 16;
}
__device__ __forceinline__ short f2bf(float f) { return (short)f2bfu(f); }

__device__ __forceinline__ float bflo(unsigned d) {
  union { unsigned u; float f; } v; v.u = d << 16; return v.f;
}
__device__ __forceinline__ float bfhi(unsigned d) {
  union { unsigned u; float f; } v; v.u = d & 0xFFFF0000u; return v.f;
}

// tanh-gelu (jax approximate=True). Overflow-safe (e=inf -> gelu=h).
__device__ __forceinline__ float gelu_f(float h) {
  const float m1 = h * h;
  const float t2u = h * fmaf(0.07135481f, m1, 1.5957691f);
  const float e = __expf(t2u);
  const float rc = __builtin_amdgcn_rcpf(1.f + e);
  return h - h * rc;
}

#define PIN(v) asm volatile("" : "+v"(v))

// ---------------------------------------------------------------------------
// Kernel 1: AB (bf16) in round-8 layout:
//   element index = n*256 + half*128 + (c&15)*8 + ((c>>4)&7)
//   value = x[n] . Wab[:,c] + 0.5*b1[c mod 128],
//   Wab[k][c] = c<128 ? W1[k][c] : W1[128+k][c-128]
// so the edge kernel's per-lane gather (cols {16*mb + r, mb=0..7} of one
// half) is one contiguous 16 B uint4.
// ---------------------------------------------------------------------------
__global__ __launch_bounds__(256) void node_kernel(
    const float* __restrict__ x, const float* __restrict__ W1,
    const float* __restrict__ b1, unsigned short* __restrict__ AB) {
  const int l = threadIdx.x & 63;
  const int wv = threadIdx.x >> 6;
  const int r = l & 15, g4 = l >> 4;

  const int wid = blockIdx.x * 4 + wv;
  const int s = wid & 3;                 // col strip: blocks mb = 4s+q
  const int half = s >> 1;
  const int sh = s & 1;                  // mb8 = 4*sh + q

  bf16x8 wA[4][4];
#pragma unroll
  for (int q = 0; q < 4; ++q) {
    const int c = 16 * (4 * s + q) + r;
    const float* Wb = (c < 128) ? (W1 + c) : (W1 + 128 * 128 + (c - 128));
#pragma unroll
    for (int ks = 0; ks < 4; ++ks) {
#pragma unroll
      for (int t = 0; t < 8; ++t)
        wA[q][ks][t] = f2bf(Wb[(size_t)(ks * 32 + g4 * 8 + t) * 128]);
      PIN(wA[q][ks]);
    }
  }
  // bias per (q, i): b1[(16*(4s+q) + 4*g4 + i) & 127]
  float bva[4][4];
#pragma unroll
  for (int q = 0; q < 4; ++q)
#pragma unroll
    for (int i = 0; i < 4; ++i)
      bva[q][i] = 0.5f * b1[(16 * (4 * s + q) + 4 * g4 + i) & 127];

  for (int t0 = wid >> 2; t0 < (N_NODES / 16); t0 += 1024) {
    const int n0 = t0 * 16;
    f32x4 acc[4] = {{0,0,0,0},{0,0,0,0},{0,0,0,0},{0,0,0,0}};
#pragma unroll
    for (int ks = 0; ks < 4; ++ks) {
      const float* xr = x + (size_t)(n0 + r) * 128 + ks * 32 + g4 * 8;
      const float4 x0 = *(const float4*)xr;
      const float4 x1 = *(const float4*)(xr + 4);
      bf16x8 xb;
      xb[0] = f2bf(x0.x); xb[1] = f2bf(x0.y); xb[2] = f2bf(x0.z); xb[3] = f2bf(x0.w);
      xb[4] = f2bf(x1.x); xb[5] = f2bf(x1.y); xb[6] = f2bf(x1.z); xb[7] = f2bf(x1.w);
#pragma unroll
      for (int q = 0; q < 4; ++q)
        acc[q] = __builtin_amdgcn_mfma_f32_16x16x32_bf16(wA[q][ks], xb, acc[q], 0, 0, 0);
    }
    // write: for rr = 4*g4+i, pack mbs {4sh..4sh+3} (q) as 4 bf16 = uint2
#pragma unroll
    for (int i = 0; i < 4; ++i) {
      uint2 pk;
      pk.x = f2bfu(acc[0][i] + bva[0][i]) | (f2bfu(acc[1][i] + bva[1][i]) << 16);
      pk.y = f2bfu(acc[2][i] + bva[2][i]) | (f2bfu(acc[3][i] + bva[3][i]) << 16);
      *(uint2*)(AB + (size_t)(n0 + r) * 256 + half * 128 + (4 * g4 + i) * 8 + 4 * sh) = pk;
    }
  }
}

// ---------------------------------------------------------------------------
// Kernel 2: fused edge kernel, transposed MFMA orientation.
// One wave = 16 edges. A = ea fragments (M = edges), B = weight fragments
// (N = feature cols, 8 blocks), D: lane holds edges m=4*g4+i, col 16*mb+r.
//  - direct coalesced stores (16 lanes = 64 B line), NO LDS transpose
//  - weights in block-shared LDS (16 KB), freeing ~64 VGPRs -> occupancy
//  - gate: 16-lane shfl_xor reduce, no broadcast needed
// ---------------------------------------------------------------------------
__global__ __launch_bounds__(256) void edge_kernel(
    const float* __restrict__ edge_attr, const int* __restrict__ edge_index,
    const unsigned short* __restrict__ AB,
    const float* __restrict__ W_proj, const float* __restrict__ b_proj,
    const float* __restrict__ W1,
    const float* __restrict__ W2, const float* __restrict__ b2,
    float* __restrict__ out) {
  __shared__ uint4 wHl[512];   // [mb][lane] fragments, 8 KB
  __shared__ uint4 wPl[512];   // 8 KB
  const int l = threadIdx.x & 63;
  const int wv = threadIdx.x >> 6;
  const int r = l & 15, g4 = l >> 4;

  // build block-shared weight fragments: id = mb*64 + lane
#pragma unroll
  for (int pp = 0; pp < 2; ++pp) {
    const int id = threadIdx.x * 2 + pp;
    const int mb = id >> 6, ln = id & 63;
    const int rr = ln & 15, gg = ln >> 4;
    union { uint4 u; bf16x8 b; } h, p;
#pragma unroll
    for (int t = 0; t < 8; ++t) {
      const int kk = gg * 8 + t;
      h.b[t] = (kk < 31) ? f2bf(W1[(size_t)(256 + kk) * 128 + 16 * mb + rr]) : (short)0;
      p.b[t] = (kk < 31) ? f2bf(W_proj[(size_t)kk * 128 + 16 * mb + rr]) : (short)0;
    }
    wHl[id] = h.u;
    wPl[id] = p.u;
  }

  float w2r[8], bpr[8];
#pragma unroll
  for (int mb = 0; mb < 8; ++mb) {
    w2r[mb] = W2[16 * mb + r];
    bpr[mb] = b_proj[16 * mb + r];
  }
  const float b2v = b2[0];
  __syncthreads();

  const int nwaves = gridDim.x * 4;
  const int NT = N_EDGES / 16;

  for (int tile = blockIdx.x * 4 + wv; tile < NT; tile += nwaves) {
    const int e0 = tile * 16 + 4 * g4;          // this lane-group's 4 edges
    const int4 s4 = *(const int4*)(edge_index + e0);
    const int4 d4 = *(const int4*)(edge_index + N_EDGES + e0);

    // ea A-frag: A[m][k], m = lane&15 = edge-within-tile, k = g4*8+t
    const float* ear = edge_attr + (size_t)(tile * 16 + r) * 31 + g4 * 8;
    bf16x8 eb;
#pragma unroll
    for (int t = 0; t < 8; ++t) {
      const int kk = g4 * 8 + t;
      eb[t] = (kk < 31) ? f2bf(ear[t]) : (short)0;
    }

    // gathers: per edge i, one 16 B uint4 per half (16-lane groups read
    // 256 B contiguous)
    uint4 ua[4], ub[4];
    ua[0] = *(const uint4*)(AB + (size_t)s4.x * 256 + r * 8);
    ua[1] = *(const uint4*)(AB + (size_t)s4.y * 256 + r * 8);
    ua[2] = *(const uint4*)(AB + (size_t)s4.z * 256 + r * 8);
    ua[3] = *(const uint4*)(AB + (size_t)s4.w * 256 + r * 8);
    ub[0] = *(const uint4*)(AB + (size_t)d4.x * 256 + 128 + r * 8);
    ub[1] = *(const uint4*)(AB + (size_t)d4.y * 256 + 128 + r * 8);
    ub[2] = *(const uint4*)(AB + (size_t)d4.z * 256 + 128 + r * 8);
    ub[3] = *(const uint4*)(AB + (size_t)d4.w * 256 + 128 + r * 8);

    // unpack + combine into C: acch[mb][i] (bf16 element mb of ua/ub[i])
    f32x4 acch[8];
#pragma unroll
    for (int mb = 0; mb < 8; ++mb) {
      const int dw = mb >> 1;
#pragma unroll
      for (int i = 0; i < 4; ++i) {
        const unsigned da = ((const unsigned*)&ua[i])[dw];
        const unsigned db = ((const unsigned*)&ub[i])[dw];
        acch[mb][i] = ((mb & 1) ? bfhi(da) : bflo(da)) +
                      ((mb & 1) ? bfhi(db) : bflo(db));
      }
    }

#pragma unroll
    for (int mb = 0; mb < 8; ++mb) {
      union { uint4 u; bf16x8 b; } w;
      w.u = wHl[mb * 64 + l];
      acch[mb] = __builtin_amdgcn_mfma_f32_16x16x32_bf16(eb, w.b, acch[mb], 0, 0, 0);
    }

    // gate: lg[i] = sum over cols; this lane's cols are 16*mb + r
    float lg[4] = {0.f, 0.f, 0.f, 0.f};
#pragma unroll
    for (int mb = 0; mb < 8; ++mb)
#pragma unroll
      for (int i = 0; i < 4; ++i)
        lg[i] = fmaf(gelu_f(acch[mb][i]), w2r[mb], lg[i]);
#pragma unroll
    for (int i = 0; i < 4; ++i) {
      lg[i] += __shfl_xor(lg[i], 1);
      lg[i] += __shfl_xor(lg[i], 2);
      lg[i] += __shfl_xor(lg[i], 4);
      lg[i] += __shfl_xor(lg[i], 8);
      lg[i] = __builtin_amdgcn_rcpf(1.f + __expf(-(lg[i] + b2v)));  // = gate
    }

    // base projection + scale + direct coalesced stores
    float* const obase = out + (size_t)e0 * 128 + r;
#pragma unroll
    for (int mb = 0; mb < 8; ++mb) {
      union { uint4 u; bf16x8 b; } w;
      w.u = wPl[mb * 64 + l];
      f32x4 ac = __builtin_amdgcn_mfma_f32_16x16x32_bf16(
          eb, w.b, (f32x4){0.f, 0.f, 0.f, 0.f}, 0, 0, 0);
#pragma unroll
      for (int i = 0; i < 4; ++i)
        obase[(size_t)i * 128 + 16 * mb] = (ac[i] + bpr[mb]) * lg[i];
    }
  }
}

extern "C" void kernel_launch(void* const* d_in, const int* in_sizes, int n_in,
                              void* d_out, int out_size, void* d_ws, size_t ws_size,
                              hipStream_t stream) {
  const float* x          = (const float*)d_in[0];
  const float* edge_attr  = (const float*)d_in[1];
  const int*   edge_index = (const int*)d_in[2];
  const float* W_proj     = (const float*)d_in[3];
  const float* b_proj     = (const float*)d_in[4];
  const float* W1         = (const float*)d_in[5];
  const float* b1         = (const float*)d_in[6];
  const float* W2         = (const float*)d_in[7];
  const float* b2         = (const float*)d_in[8];
  float* out = (float*)d_out;
  unsigned short* AB = (unsigned short*)d_ws;  // 50000*256 bf16 = 25.6 MB

  hipLaunchKernelGGL(node_kernel, dim3(1024), dim3(256), 0, stream,
                     x, W1, b1, AB);
  hipLaunchKernelGGL(edge_kernel, dim3(2048), dim3(256), 0, stream,
                     edge_attr, edge_index, AB, W_proj, b_proj, W1, W2, b2,
                     out);
}